// Round 3
// baseline (855.392 us; speedup 1.0000x reference)
//
#include <hip/hip_runtime.h>
#include <math.h>

// Shapes (fixed)
#define BB 8
#define SEQ 2049
#define NT 2048
#define DD 1024
#define EE 8
#define SS 256
#define ESN 2048
#define HH 512

typedef __bf16 bf16x8 __attribute__((ext_vector_type(8)));
typedef float f32x4 __attribute__((ext_vector_type(4)));

__device__ __forceinline__ float gelu_f(float v) {
  return 0.5f * v * (1.0f + erff(v * 0.70710678118654752440f));
}
__device__ __forceinline__ float wave_sum(float v) {
#pragma unroll
  for (int off = 1; off < 64; off <<= 1) v += __shfl_xor(v, off);
  return v;
}
__device__ __forceinline__ unsigned short f2bf(float f) {
  unsigned int u = __float_as_uint(f);
  u = (u + 0x7fffu + ((u >> 16) & 1u)) >> 16;
  return (unsigned short)u;
}
__device__ __forceinline__ float bf2f(unsigned short h) {
  return __uint_as_float(((unsigned int)h) << 16);
}

// async 16B/lane global->LDS stage; lbase is wave-uniform, HW adds lane*16.
__device__ __forceinline__ void stage16(const unsigned short* g, unsigned short* lbase, int lane) {
#if __has_builtin(__builtin_amdgcn_global_load_lds)
  __builtin_amdgcn_global_load_lds((const __attribute__((address_space(1))) void*)g,
                                   (__attribute__((address_space(3))) void*)lbase, 16, 0, 0);
#else
  *(int4*)(lbase + lane * 8) = *(const int4*)g;
#endif
}

// XCD-aware bijective block remap (grid size must be divisible by 8).
__device__ __forceinline__ int3 xcd_map() {
  const int gx = gridDim.x, gy = gridDim.y;
  int bid = blockIdx.x + gx * (blockIdx.y + gy * blockIdx.z);
  const int q = (gx * gy * (int)gridDim.z) >> 3;
  bid = (bid & 7) * q + (bid >> 3);
  int3 r;
  r.x = bid % gx; bid /= gx;
  r.y = bid % gy;
  r.z = bid / gy;
  return r;
}

// ---- bf16 gemm_bt core v2: C[128x128] = A[m][k]*B[n][k]^T, K%128==0 ----
// BK=64, double-buffered LDS (2 x 32KB), stage-early 2-phase, 1 barrier/step.
// LDS layout (shorts): buf p: A: p*16384 + kk*4096 + row*32 + chunk*8
//                             B: +8192.  chunk is XOR-swizzled: c' = c ^ ((row>>1)&3).
__device__ __forceinline__ void gemm_core(const unsigned short* __restrict__ A,
                                          const unsigned short* __restrict__ B,
                                          int K, unsigned short* LDS, f32x4 acc[4][4]) {
  const int t = threadIdx.x;
  const int lane = t & 63, wave = t >> 6;
  const int fr = lane & 15;
  const int wm = (wave >> 1) * 64, wn = (wave & 1) * 64;
  // staging lane constants (source pre-swizzle; LDS dest stays linear)
  const int sc = ((lane & 3) ^ ((lane >> 3) & 3)) * 8;   // shorts
  const int srw = lane >> 2;                              // row within 16-row stripe
  // fragment-read lane constants (same involution)
  const int swz = ((lane >> 4) ^ ((fr >> 1) & 3)) * 8;    // shorts
  const int aoff = (wm + fr) * 32 + swz;
  const int boff = 8192 + (wn + fr) * 32 + swz;

  auto STAGE = [&](int pb, int k0) {
#pragma unroll
    for (int q = 0; q < 4; ++q) {
      const int kk = q & 1, rb = q >> 1;
      const int row = rb * 64 + wave * 16 + srw;
      stage16(A + (size_t)row * K + k0 + kk * 32 + sc,
              LDS + pb + kk * 4096 + rb * 2048 + wave * 512, lane);
      stage16(B + (size_t)row * K + k0 + kk * 32 + sc,
              LDS + pb + 8192 + kk * 4096 + rb * 2048 + wave * 512, lane);
    }
  };
  auto COMPUTE = [&](int pb) {
#pragma unroll
    for (int kk = 0; kk < 2; ++kk) {
      bf16x8 af[4], bq[4];
#pragma unroll
      for (int i = 0; i < 4; ++i)
        af[i] = *(const bf16x8*)(LDS + pb + kk * 4096 + i * 512 + aoff);
#pragma unroll
      for (int j = 0; j < 4; ++j)
        bq[j] = *(const bf16x8*)(LDS + pb + kk * 4096 + j * 512 + boff);
#pragma unroll
      for (int i = 0; i < 4; ++i)
#pragma unroll
        for (int j = 0; j < 4; ++j)
          acc[i][j] = __builtin_amdgcn_mfma_f32_16x16x32_bf16(af[i], bq[j], acc[i][j], 0, 0, 0);
    }
  };

  STAGE(0, 0);
  __syncthreads();
  const int nt = K >> 6;
  for (int tt = 0; tt < nt; tt += 2) {
    STAGE(16384, (tt + 1) << 6);   // prefetch odd tile while computing even
    COMPUTE(0);
    __syncthreads();               // drains vmcnt+lgkmcnt
    if (tt + 2 < nt) STAGE(0, (tt + 2) << 6);
    COMPUTE(1);
    __syncthreads();
  }
}

#define GEMM_PRE()                                        \
  __shared__ unsigned short LDS[32768];                   \
  f32x4 acc[4][4];                                        \
  _Pragma("unroll") for (int i = 0; i < 4; ++i)           \
  _Pragma("unroll") for (int j = 0; j < 4; ++j)           \
  _Pragma("unroll") for (int r = 0; r < 4; ++r) acc[i][j][r] = 0.f;

#define GEMM_EPI_VARS()                                   \
  const int lane = threadIdx.x & 63, wave = threadIdx.x >> 6; \
  const int wm = (wave >> 1) * 64, wn = (wave & 1) * 64;  \
  const int fr16 = lane & 15, r4 = (lane >> 4) << 2;

// logits -> E16[n][c] (scalar) + ET[c][n] (packed 8B)
__global__ __launch_bounds__(256) void k_logits_mfma(const unsigned short* __restrict__ Xb,
    const unsigned short* __restrict__ MT, unsigned short* __restrict__ E16,
    unsigned short* __restrict__ ET) {
  GEMM_PRE();
  const int3 bi = xcd_map();
  const int b = bi.z, m0 = bi.x * 128, n0 = bi.y * 128;
  gemm_core(Xb + ((size_t)b * NT + m0) * DD, MT + (size_t)n0 * DD, DD, LDS, acc);
  GEMM_EPI_VARS();
  unsigned short* o = E16 + (size_t)b * NT * ESN;
#pragma unroll
  for (int i = 0; i < 4; ++i)
#pragma unroll
    for (int j = 0; j < 4; ++j) {
      const int gmb = m0 + wm + i * 16 + r4;
      const int gn = n0 + wn + j * 16 + fr16;
      ushort4 pk;
      pk.x = f2bf(expf(acc[i][j][0]));
      pk.y = f2bf(expf(acc[i][j][1]));
      pk.z = f2bf(expf(acc[i][j][2]));
      pk.w = f2bf(expf(acc[i][j][3]));
      o[(size_t)(gmb + 0) * ESN + gn] = pk.x;
      o[(size_t)(gmb + 1) * ESN + gn] = pk.y;
      o[(size_t)(gmb + 2) * ESN + gn] = pk.z;
      o[(size_t)(gmb + 3) * ESN + gn] = pk.w;
      *(ushort4*)(ET + ((size_t)b * ESN + gn) * NT + gmb) = pk;
    }
}

__global__ __launch_bounds__(256) void k_slotin_mfma(const unsigned short* __restrict__ ET,
    const unsigned short* __restrict__ XT, const float* __restrict__ cinv,
    unsigned short* __restrict__ SI) {
  GEMM_PRE();
  const int3 bi = xcd_map();
  const int b = bi.z, m0 = bi.x * 128, n0 = bi.y * 128;
  gemm_core(ET + ((size_t)b * ESN + m0) * NT, XT + ((size_t)b * DD + n0) * NT, NT, LDS, acc);
  GEMM_EPI_VARS();
#pragma unroll
  for (int i = 0; i < 4; ++i)
#pragma unroll
    for (int j = 0; j < 4; ++j) {
      const int gmb = m0 + wm + i * 16 + r4;
      const int gn = n0 + wn + j * 16 + fr16;
#pragma unroll
      for (int r = 0; r < 4; ++r)
        SI[((size_t)b * ESN + gmb + r) * DD + gn] = f2bf(acc[i][j][r] * cinv[b * ESN + gmb + r]);
    }
}

__global__ __launch_bounds__(256) void k_ffn1_mfma(const unsigned short* __restrict__ SI,
    const unsigned short* __restrict__ w1b, const float* __restrict__ b1,
    unsigned short* __restrict__ H1) {
  GEMM_PRE();
  const int3 bi = xcd_map();
  const int z = bi.z, b = z >> 3, e = z & 7;
  const int m0 = bi.x * 128, n0 = bi.y * 128;
  gemm_core(SI + ((size_t)b * ESN + e * SS + m0) * DD, w1b + ((size_t)e * HH + n0) * DD,
            DD, LDS, acc);
  GEMM_EPI_VARS();
#pragma unroll
  for (int i = 0; i < 4; ++i)
#pragma unroll
    for (int j = 0; j < 4; ++j) {
      const int gmb = m0 + wm + i * 16 + r4;
      const int gn = n0 + wn + j * 16 + fr16;
      const float bias = b1[e * HH + gn];
#pragma unroll
      for (int r = 0; r < 4; ++r)
        H1[((size_t)(b * EE + e) * SS + gmb + r) * HH + gn] = f2bf(gelu_f(acc[i][j][r] + bias));
    }
}

// ffn2 writes SOT[d][c] directly (packed 8B over the 4 consecutive c rows)
__global__ __launch_bounds__(256) void k_ffn2_mfma(const unsigned short* __restrict__ H1,
    const unsigned short* __restrict__ w2b, const float* __restrict__ b2,
    unsigned short* __restrict__ SOT) {
  GEMM_PRE();
  const int3 bi = xcd_map();
  const int z = bi.z, b = z >> 3, e = z & 7;
  const int m0 = bi.x * 128, n0 = bi.y * 128;
  gemm_core(H1 + ((size_t)(b * EE + e) * SS + m0) * HH, w2b + ((size_t)e * DD + n0) * HH,
            HH, LDS, acc);
  GEMM_EPI_VARS();
#pragma unroll
  for (int i = 0; i < 4; ++i)
#pragma unroll
    for (int j = 0; j < 4; ++j) {
      const int gmb = m0 + wm + i * 16 + r4;   // s within expert
      const int gn = n0 + wn + j * 16 + fr16;  // d
      const float bias = b2[e * DD + gn];
      ushort4 pk;
      pk.x = f2bf(acc[i][j][0] + bias);
      pk.y = f2bf(acc[i][j][1] + bias);
      pk.z = f2bf(acc[i][j][2] + bias);
      pk.w = f2bf(acc[i][j][3] + bias);
      *(ushort4*)(SOT + ((size_t)b * DD + gn) * ESN + e * SS + gmb) = pk;
    }
}

__global__ __launch_bounds__(256) void k_img_mfma(const unsigned short* __restrict__ E16,
    const unsigned short* __restrict__ SOT, const float* __restrict__ rinv,
    float* __restrict__ out) {
  GEMM_PRE();
  const int3 bi = xcd_map();
  const int b = bi.z, m0 = bi.x * 128, n0 = bi.y * 128;
  gemm_core(E16 + ((size_t)b * NT + m0) * ESN, SOT + ((size_t)b * DD + n0) * ESN,
            ESN, LDS, acc);
  GEMM_EPI_VARS();
#pragma unroll
  for (int i = 0; i < 4; ++i)
#pragma unroll
    for (int j = 0; j < 4; ++j) {
      const int gmb = m0 + wm + i * 16 + r4;
      const int gn = n0 + wn + j * 16 + fr16;
#pragma unroll
      for (int r = 0; r < 4; ++r)
        out[((size_t)b * SEQ + 1 + gmb + r) * DD + gn] = acc[i][j][r] * rinv[b * NT + gmb + r];
    }
}

// -------- packing --------
__global__ __launch_bounds__(256) void k_xnf(const float* __restrict__ x, float* __restrict__ xnf) {
  const int wid = blockIdx.x * 4 + (threadIdx.x >> 6);
  const int lane = threadIdx.x & 63;
  const int b = wid >> 11;
  const float* row = x + ((size_t)b * SEQ + 1 + (wid & (NT - 1))) * DD;
  float s = 0.f;
#pragma unroll
  for (int k = 0; k < DD / 64; ++k) { const float v = row[lane + k * 64]; s = fmaf(v, v, s); }
  s = wave_sum(s);
  if (lane == 0) xnf[wid] = 1.0f / fmaxf(sqrtf(s), 1e-12f);
}

__global__ __launch_bounds__(256) void k_munf(const float* __restrict__ mu,
    const float* __restrict__ scale, float* __restrict__ munf) {
  __shared__ float part[4][64];
  const int c0 = blockIdx.x * 64;
  const int ci = threadIdx.x & 63, dg = threadIdx.x >> 6;
  float s = 0.f;
  for (int d = dg; d < DD; d += 4) { const float v = mu[(size_t)d * ESN + c0 + ci]; s = fmaf(v, v, s); }
  part[dg][ci] = s;
  __syncthreads();
  if (threadIdx.x < 64) {
    const float t = part[0][ci] + part[1][ci] + part[2][ci] + part[3][ci];
    munf[c0 + ci] = scale[0] / fmaxf(sqrtf(t), 1e-12f);
  }
}

__global__ __launch_bounds__(256) void k_pack_x(const float* __restrict__ x,
    const float* __restrict__ xnf, unsigned short* __restrict__ Xb,
    unsigned short* __restrict__ XT) {
  __shared__ unsigned short tile[64][72];
  const int b = blockIdx.z, n0 = blockIdx.x * 64, d0 = blockIdx.y * 64;
  const int t = threadIdx.x, tr = t >> 2, tc = (t & 3) * 16;
  const float* s = x + ((size_t)b * SEQ + 1 + n0 + tr) * DD + d0 + tc;
  const float xs = xnf[b * NT + n0 + tr];
  unsigned short tmp[16];
#pragma unroll
  for (int j = 0; j < 16; j += 4) {
    float4 v = *(const float4*)(s + j);
    tmp[j] = f2bf(v.x * xs); tmp[j + 1] = f2bf(v.y * xs);
    tmp[j + 2] = f2bf(v.z * xs); tmp[j + 3] = f2bf(v.w * xs);
  }
  *(int4*)&tile[tr][tc] = *(int4*)tmp;
  *(int4*)&tile[tr][tc + 8] = *(int4*)(tmp + 8);
  unsigned short* xb = Xb + ((size_t)b * NT + n0 + tr) * DD + d0 + tc;
  *(int4*)xb = *(int4*)tmp;
  *(int4*)(xb + 8) = *(int4*)(tmp + 8);
  __syncthreads();
  unsigned short* d = XT + ((size_t)b * DD + d0 + tr) * NT + n0 + tc;
#pragma unroll
  for (int j = 0; j < 16; ++j) tmp[j] = tile[tc + j][tr];
  *(int4*)d = *(int4*)tmp;
  *(int4*)(d + 8) = *(int4*)(tmp + 8);
}

__global__ __launch_bounds__(256) void k_pack_mu(const float* __restrict__ mu,
    const float* __restrict__ munf, unsigned short* __restrict__ MT) {
  __shared__ unsigned short tile[64][72];
  const int d0 = blockIdx.x * 64, c0 = blockIdx.y * 64;
  const int t = threadIdx.x, tr = t >> 2, tc = (t & 3) * 16;
  const float* s = mu + (size_t)(d0 + tr) * ESN + c0 + tc;
  unsigned short tmp[16];
#pragma unroll
  for (int j = 0; j < 16; j += 4) {
    float4 v = *(const float4*)(s + j);
    tmp[j] = f2bf(v.x * munf[c0 + tc + j]);
    tmp[j + 1] = f2bf(v.y * munf[c0 + tc + j + 1]);
    tmp[j + 2] = f2bf(v.z * munf[c0 + tc + j + 2]);
    tmp[j + 3] = f2bf(v.w * munf[c0 + tc + j + 3]);
  }
  *(int4*)&tile[tr][tc] = *(int4*)tmp;
  *(int4*)&tile[tr][tc + 8] = *(int4*)(tmp + 8);
  __syncthreads();
  unsigned short* d = MT + (size_t)(c0 + tr) * DD + d0 + tc;
#pragma unroll
  for (int j = 0; j < 16; ++j) tmp[j] = tile[tc + j][tr];
  *(int4*)d = *(int4*)tmp;
  *(int4*)(d + 8) = *(int4*)(tmp + 8);
}

__global__ __launch_bounds__(256) void k_packw(const float* __restrict__ w,
    unsigned short* __restrict__ o, int n4) {
  const int i = blockIdx.x * 256 + threadIdx.x;
  if (i < n4) {
    float4 v = ((const float4*)w)[i];
    ushort4 u;
    u.x = f2bf(v.x); u.y = f2bf(v.y); u.z = f2bf(v.z); u.w = f2bf(v.w);
    ((ushort4*)o)[i] = u;
  }
}

// -------- softmax stats --------
__global__ __launch_bounds__(256) void k_rowstats_e(const unsigned short* __restrict__ E,
    float* __restrict__ rinv, float* __restrict__ t_r2, float* __restrict__ t_dr) {
  const int wid = blockIdx.x * 4 + (threadIdx.x >> 6);  // b*NT + n
  const int lane = threadIdx.x & 63;
  const int n = wid & (NT - 1);
  const unsigned short* row = E + (size_t)wid * ESN;
  float s1 = 0.f, s2 = 0.f;
#pragma unroll
  for (int it = 0; it < 4; ++it) {
    int4 v = *(const int4*)(row + it * 512 + lane * 8);
    const unsigned short* u = (const unsigned short*)&v;
#pragma unroll
    for (int j = 0; j < 8; ++j) { const float e = bf2f(u[j]); s1 += e; s2 = fmaf(e, e, s2); }
  }
  s1 = wave_sum(s1); s2 = wave_sum(s2);
  if (lane == 0) {
    const float ri = 1.0f / s1;
    rinv[wid] = ri;
    const float r2 = 1.0f / (s2 * ri * ri + 1e-9f);
    t_r2[wid] = r2;
    t_dr[wid] = bf2f(row[n]) * ri * r2;
  }
}

// column stats over ET rows (coalesced)
__global__ __launch_bounds__(256) void k_colstats(const unsigned short* __restrict__ ET,
    float* __restrict__ cinv, float* __restrict__ t_rs2, float* __restrict__ t_sd) {
  const int wid = blockIdx.x * 4 + (threadIdx.x >> 6);  // b*ESN + c
  const int lane = threadIdx.x & 63;
  const unsigned short* row = ET + (size_t)wid * NT;
  float s1 = 0.f, s2 = 0.f;
#pragma unroll
  for (int it = 0; it < 4; ++it) {
    int4 v = *(const int4*)(row + it * 512 + lane * 8);
    const unsigned short* u = (const unsigned short*)&v;
#pragma unroll
    for (int j = 0; j < 8; ++j) { const float e = bf2f(u[j]); s1 += e; s2 = fmaf(e, e, s2); }
  }
  s1 = wave_sum(s1); s2 = wave_sum(s2);
  if (lane == 0) {
    const float ci = 1.0f / s1;
    cinv[wid] = ci;
    const float rs2 = 1.0f / (s2 * ci * ci + 1e-9f);
    t_rs2[wid] = rs2;
    const int c = wid & (ESN - 1);
    t_sd[wid] = ((c % 257) == 0) ? rs2 : 0.f;
  }
}

// -------- cls path --------
__global__ __launch_bounds__(256) void k_clsA(const float* __restrict__ x,
    const float* __restrict__ w1, const float* __restrict__ b1, float* __restrict__ clsh) {
  const int wid = blockIdx.x * 4 + (threadIdx.x >> 6);
  const int lane = threadIdx.x & 63;
  const int b = wid >> 9, h = wid & (HH - 1);
  const float* xr = x + (size_t)b * SEQ * DD;
  const float* wr = w1 + (size_t)h * DD;
  float s = 0.f;
#pragma unroll
  for (int k = 0; k < DD / 64; ++k) s = fmaf(xr[lane + k * 64], wr[lane + k * 64], s);
  s = wave_sum(s);
  if (lane == 0) clsh[wid] = gelu_f(s + b1[h]);
}

__global__ __launch_bounds__(256) void k_clsB(const float* __restrict__ clsh,
    const float* __restrict__ w2, const float* __restrict__ b2, float* __restrict__ out) {
  const int wid = blockIdx.x * 4 + (threadIdx.x >> 6);
  const int lane = threadIdx.x & 63;
  const int b = wid >> 10, d = wid & (DD - 1);
  const float* hr = clsh + (size_t)b * HH;
  const float* wr = w2 + (size_t)d * HH;
  float s = 0.f;
#pragma unroll
  for (int k = 0; k < HH / 64; ++k) s = fmaf(hr[lane + k * 64], wr[lane + k * 64], s);
  s = wave_sum(s);
  if (lane == 0) out[(size_t)b * SEQ * DD + d] = s + b2[d];
}

__global__ __launch_bounds__(256) void k_metrics(const float* __restrict__ t_r2,
    const float* __restrict__ t_dr, const float* __restrict__ t_rs2,
    const float* __restrict__ t_sd, float* __restrict__ out) {
  __shared__ float sm[256];
  const int tid = threadIdx.x;
  float a = 0.f, b = 0.f, c = 0.f, d = 0.f;
  for (int i = tid; i < BB * NT; i += 256) { a += t_r2[i]; b += t_dr[i]; }
  for (int i = tid; i < BB * ESN; i += 256) { c += t_rs2[i]; d += t_sd[i]; }
  float vals[4] = {a, b, c, d};
  float res[4];
#pragma unroll
  for (int v = 0; v < 4; ++v) {
    sm[tid] = vals[v];
    __syncthreads();
    for (int s = 128; s > 0; s >>= 1) {
      if (tid < s) sm[tid] += sm[tid + s];
      __syncthreads();
    }
    res[v] = sm[0];
    __syncthreads();
  }
  if (tid == 0) {
    out[(size_t)BB * SEQ * DD] = (res[0] - res[1]) / 33538048.0f;
    out[(size_t)BB * SEQ * DD + 1] = (res[2] - res[3]) / 33538048.0f;
  }
}

extern "C" void kernel_launch(void* const* d_in, const int* in_sizes, int n_in,
                              void* d_out, int out_size, void* d_ws, size_t ws_size,
                              hipStream_t stream) {
  const float* x      = (const float*)d_in[0];
  const float* mu     = (const float*)d_in[1];
  const float* scale  = (const float*)d_in[2];
  const float* cls_w1 = (const float*)d_in[3];
  const float* cls_b1 = (const float*)d_in[4];
  const float* cls_w2 = (const float*)d_in[5];
  const float* cls_b2 = (const float*)d_in[6];
  const float* w1     = (const float*)d_in[7];
  const float* b1     = (const float*)d_in[8];
  const float* w2     = (const float*)d_in[9];
  const float* b2     = (const float*)d_in[10];
  float* out = (float*)d_out;

  // workspace plan (bytes), aliasing by lifetime:
  char* W = (char*)d_ws;
  unsigned short* XT  = (unsigned short*)(W);              // 32MB; H1 aliases after slotin
  unsigned short* Xb  = (unsigned short*)(W + 33554432);   // 32MB; SOT aliases after logits
  unsigned short* MT  = (unsigned short*)(W + 67108864);   //  4MB
  unsigned short* E16 = (unsigned short*)(W + 71303168);   // 64MB (lives until img)
  unsigned short* ET  = (unsigned short*)(W + 138412032);  // 64MB; w1b/w2b alias after colstats+slotin
  unsigned short* SI  = (unsigned short*)(W + 205520896);  // 32MB
  unsigned short* H1  = (unsigned short*)(W);              // 16MB (alias XT)
  unsigned short* SOT = (unsigned short*)(W + 33554432);   // 32MB (alias Xb)
  unsigned short* w1b = (unsigned short*)(W + 138412032);  //  8MB (alias ET)
  unsigned short* w2b = (unsigned short*)(W + 146800640);  //  8MB (alias ET)
  float* F = (float*)(W + 239075328);
  float* xnf   = F;
  float* munf  = F + 16384;
  float* rinv  = F + 18432;
  float* t_r2  = F + 34816;
  float* t_dr  = F + 51200;
  float* cinv  = F + 67584;
  float* t_rs2 = F + 83968;
  float* t_sd  = F + 100352;
  float* clsh  = F + 116736;   // end ~228.5MB

  k_xnf<<<dim3(BB * NT / 4), 256, 0, stream>>>(x, xnf);
  k_munf<<<dim3(ESN / 64), 256, 0, stream>>>(mu, scale, munf);
  k_pack_x<<<dim3(NT / 64, DD / 64, BB), 256, 0, stream>>>(x, xnf, Xb, XT);
  k_pack_mu<<<dim3(DD / 64, ESN / 64), 256, 0, stream>>>(mu, munf, MT);
  k_logits_mfma<<<dim3(NT / 128, ESN / 128, BB), 256, 0, stream>>>(Xb, MT, E16, ET);
  k_rowstats_e<<<dim3(BB * NT / 4), 256, 0, stream>>>(E16, rinv, t_r2, t_dr);
  k_colstats<<<dim3(BB * ESN / 4), 256, 0, stream>>>(ET, cinv, t_rs2, t_sd);
  k_slotin_mfma<<<dim3(ESN / 128, DD / 128, BB), 256, 0, stream>>>(ET, XT, cinv, SI);
  k_packw<<<dim3(EE * HH * DD / 4 / 256), 256, 0, stream>>>(w1, w1b, EE * HH * DD / 4);
  k_packw<<<dim3(EE * DD * HH / 4 / 256), 256, 0, stream>>>(w2, w2b, EE * DD * HH / 4);
  k_ffn1_mfma<<<dim3(SS / 128, HH / 128, BB * EE), 256, 0, stream>>>(SI, w1b, b1, H1);
  k_ffn2_mfma<<<dim3(SS / 128, DD / 128, BB * EE), 256, 0, stream>>>(H1, w2b, b2, SOT);
  k_img_mfma<<<dim3(NT / 128, DD / 128, BB), 256, 0, stream>>>(E16, SOT, rinv, out);
  k_clsA<<<dim3(BB * HH / 4), 256, 0, stream>>>(x, cls_w1, cls_b1, clsh);
  k_clsB<<<dim3(BB * DD / 4), 256, 0, stream>>>(clsh, cls_w2, cls_b2, out);
  k_metrics<<<1, 256, 0, stream>>>(t_r2, t_dr, t_rs2, t_sd, out);
}

// Round 4
// 815.897 us; speedup vs baseline: 1.0484x; 1.0484x over previous
//
#include <hip/hip_runtime.h>
#include <math.h>

// Shapes (fixed)
#define BB 8
#define SEQ 2049
#define NT 2048
#define DD 1024
#define EE 8
#define SS 256
#define ESN 2048
#define HH 512

typedef __bf16 bf16x8 __attribute__((ext_vector_type(8)));
typedef float f32x4 __attribute__((ext_vector_type(4)));

__device__ __forceinline__ float gelu_f(float v) {
  return 0.5f * v * (1.0f + erff(v * 0.70710678118654752440f));
}
__device__ __forceinline__ float wave_sum(float v) {
#pragma unroll
  for (int off = 1; off < 64; off <<= 1) v += __shfl_xor(v, off);
  return v;
}
__device__ __forceinline__ unsigned short f2bf(float f) {
  unsigned int u = __float_as_uint(f);
  u = (u + 0x7fffu + ((u >> 16) & 1u)) >> 16;
  return (unsigned short)u;
}
__device__ __forceinline__ float bf2f(unsigned short h) {
  return __uint_as_float(((unsigned int)h) << 16);
}

// async 16B/lane global->LDS stage; lbase is wave-uniform, HW adds lane*16.
__device__ __forceinline__ void stage16(const unsigned short* g, unsigned short* lbase, int lane) {
#if __has_builtin(__builtin_amdgcn_global_load_lds)
  __builtin_amdgcn_global_load_lds((const __attribute__((address_space(1))) void*)g,
                                   (__attribute__((address_space(3))) void*)lbase, 16, 0, 0);
#else
  *(int4*)(lbase + lane * 8) = *(const int4*)g;
#endif
}

// XCD-aware bijective block remap (grid size must be divisible by 8).
__device__ __forceinline__ int3 xcd_map() {
  const int gx = gridDim.x, gy = gridDim.y;
  int bid = blockIdx.x + gx * (blockIdx.y + gy * blockIdx.z);
  const int q = (gx * gy * (int)gridDim.z) >> 3;
  bid = (bid & 7) * q + (bid >> 3);
  int3 r;
  r.x = bid % gx; bid /= gx;
  r.y = bid % gy;
  r.z = bid / gy;
  return r;
}

// ---- bf16 gemm_bt core: C[128x128] = A[m][k]*B[n][k]^T, K%64==0 ----
// BK=32, double-buffered LDS (2 x 16KB), stage-early 2-phase, 1 barrier/step.
// LDS (shorts): buf p at p (0/8192): A rows [128][32] at row*32, B at +4096.
// k-chunk XOR-swizzle: phys = logical ^ ((row>>1)&3); applied on the global
// SOURCE address when staging (dest stays linear) and on fragment reads.
__device__ __forceinline__ void gemm_core(const unsigned short* __restrict__ A,
                                          const unsigned short* __restrict__ B,
                                          int K, unsigned short* LDS, f32x4 acc[4][4]) {
  const int t = threadIdx.x;
  const int lane = t & 63, wave = t >> 6;
  const int fr = lane & 15;
  const int wm = (wave >> 1) * 64, wn = (wave & 1) * 64;
  const int sc = ((lane & 3) ^ ((lane >> 3) & 3)) * 8;   // source pre-swizzle (shorts)
  const int srw = lane >> 2;                              // row within 16-row stripe
  const int swz = ((lane >> 4) ^ ((fr >> 1) & 3)) * 8;    // fragment-read swizzle
  const int aoff = (wm + fr) * 32 + swz;
  const int boff = 4096 + (wn + fr) * 32 + swz;

  auto STAGE = [&](int pb, int k0) {
#pragma unroll
    for (int rb = 0; rb < 2; ++rb) {
      const int row = rb * 64 + wave * 16 + srw;
      stage16(A + (size_t)row * K + k0 + sc, LDS + pb + rb * 2048 + wave * 512, lane);
      stage16(B + (size_t)row * K + k0 + sc, LDS + pb + 4096 + rb * 2048 + wave * 512, lane);
    }
  };
  auto COMPUTE = [&](int pb) {
    bf16x8 af[4], bq[4];
#pragma unroll
    for (int i = 0; i < 4; ++i) af[i] = *(const bf16x8*)(LDS + pb + i * 512 + aoff);
#pragma unroll
    for (int j = 0; j < 4; ++j) bq[j] = *(const bf16x8*)(LDS + pb + j * 512 + boff);
#pragma unroll
    for (int i = 0; i < 4; ++i)
#pragma unroll
      for (int j = 0; j < 4; ++j)
        acc[i][j] = __builtin_amdgcn_mfma_f32_16x16x32_bf16(af[i], bq[j], acc[i][j], 0, 0, 0);
  };

  STAGE(0, 0);
  __syncthreads();
  const int nt = K >> 5;   // always even here (K % 64 == 0)
  for (int tt = 0; tt < nt; tt += 2) {
    STAGE(8192, (tt + 1) << 5);   // prefetch odd tile while computing even
    COMPUTE(0);
    __syncthreads();
    if (tt + 2 < nt) STAGE(0, (tt + 2) << 5);
    COMPUTE(1);
    __syncthreads();
  }
}

#define GEMM_PRE(LDSN)                                    \
  __shared__ unsigned short LDS[LDSN];                    \
  f32x4 acc[4][4];                                        \
  _Pragma("unroll") for (int i = 0; i < 4; ++i)           \
  _Pragma("unroll") for (int j = 0; j < 4; ++j)           \
  _Pragma("unroll") for (int r = 0; r < 4; ++r) acc[i][j][r] = 0.f;

#define GEMM_EPI_VARS()                                   \
  const int lane = threadIdx.x & 63, wave = threadIdx.x >> 6; \
  const int wm = (wave >> 1) * 64, wn = (wave & 1) * 64;  \
  const int fr16 = lane & 15, r4 = (lane >> 4) << 2;

// logits -> E16[n][c] direct (32B runs) + ET[c][n] via LDS transpose (256B runs)
__global__ __launch_bounds__(256) void k_logits_mfma(const unsigned short* __restrict__ Xb,
    const unsigned short* __restrict__ MT, unsigned short* __restrict__ E16,
    unsigned short* __restrict__ ET) {
  GEMM_PRE(16896);   // max(gemm 16384, transpose tile 128*132)
  const int3 bi = xcd_map();
  const int b = bi.z, m0 = bi.x * 128, n0 = bi.y * 128;
  gemm_core(Xb + ((size_t)b * NT + m0) * DD, MT + (size_t)n0 * DD, DD, LDS, acc);
  GEMM_EPI_VARS();
  unsigned short* o = E16 + (size_t)b * NT * ESN;
#pragma unroll
  for (int i = 0; i < 4; ++i)
#pragma unroll
    for (int j = 0; j < 4; ++j) {
      const int gmb = m0 + wm + i * 16 + r4;
      const int gn = n0 + wn + j * 16 + fr16;
      ushort4 pk;
      pk.x = f2bf(expf(acc[i][j][0]));
      pk.y = f2bf(expf(acc[i][j][1]));
      pk.z = f2bf(expf(acc[i][j][2]));
      pk.w = f2bf(expf(acc[i][j][3]));
      o[(size_t)(gmb + 0) * ESN + gn] = pk.x;
      o[(size_t)(gmb + 1) * ESN + gn] = pk.y;
      o[(size_t)(gmb + 2) * ESN + gn] = pk.z;
      o[(size_t)(gmb + 3) * ESN + gn] = pk.w;
      // LDS tile T[n][m], stride 132 shorts (8B-aligned, conflict-free)
      *(ushort4*)(LDS + (wn + j * 16 + fr16) * 132 + wm + i * 16 + r4) = pk;
    }
  __syncthreads();
  const int t = threadIdx.x;
#pragma unroll
  for (int jj = 0; jj < 8; ++jj) {
    const int nl = (t >> 4) + jj * 16;
    const int ml = (t & 15) * 8;
    int4 v = *(const int4*)(LDS + nl * 132 + ml);
    *(int4*)(ET + ((size_t)b * ESN + n0 + nl) * NT + m0 + ml) = v;
  }
}

__global__ __launch_bounds__(256) void k_slotin_mfma(const unsigned short* __restrict__ ET,
    const unsigned short* __restrict__ XT, const float* __restrict__ cinv,
    unsigned short* __restrict__ SI) {
  GEMM_PRE(16384);
  const int3 bi = xcd_map();
  const int b = bi.z, m0 = bi.x * 128, n0 = bi.y * 128;
  gemm_core(ET + ((size_t)b * ESN + m0) * NT, XT + ((size_t)b * DD + n0) * NT, NT, LDS, acc);
  GEMM_EPI_VARS();
#pragma unroll
  for (int i = 0; i < 4; ++i)
#pragma unroll
    for (int j = 0; j < 4; ++j) {
      const int gmb = m0 + wm + i * 16 + r4;
      const int gn = n0 + wn + j * 16 + fr16;
#pragma unroll
      for (int r = 0; r < 4; ++r)
        SI[((size_t)b * ESN + gmb + r) * DD + gn] = f2bf(acc[i][j][r] * cinv[b * ESN + gmb + r]);
    }
}

__global__ __launch_bounds__(256) void k_ffn1_mfma(const unsigned short* __restrict__ SI,
    const unsigned short* __restrict__ w1b, const float* __restrict__ b1,
    unsigned short* __restrict__ H1) {
  GEMM_PRE(16384);
  const int3 bi = xcd_map();
  const int z = bi.z, b = z >> 3, e = z & 7;
  const int m0 = bi.x * 128, n0 = bi.y * 128;
  gemm_core(SI + ((size_t)b * ESN + e * SS + m0) * DD, w1b + ((size_t)e * HH + n0) * DD,
            DD, LDS, acc);
  GEMM_EPI_VARS();
#pragma unroll
  for (int i = 0; i < 4; ++i)
#pragma unroll
    for (int j = 0; j < 4; ++j) {
      const int gmb = m0 + wm + i * 16 + r4;
      const int gn = n0 + wn + j * 16 + fr16;
      const float bias = b1[e * HH + gn];
#pragma unroll
      for (int r = 0; r < 4; ++r)
        H1[((size_t)(b * EE + e) * SS + gmb + r) * HH + gn] = f2bf(gelu_f(acc[i][j][r] + bias));
    }
}

// ffn2 -> SOT[d][c] via LDS transpose (coalesced 256B segments)
__global__ __launch_bounds__(256) void k_ffn2_mfma(const unsigned short* __restrict__ H1,
    const unsigned short* __restrict__ w2b, const float* __restrict__ b2,
    unsigned short* __restrict__ SOT) {
  GEMM_PRE(16896);
  const int3 bi = xcd_map();
  const int z = bi.z, b = z >> 3, e = z & 7;
  const int m0 = bi.x * 128, n0 = bi.y * 128;   // m: s within expert, n: d
  gemm_core(H1 + ((size_t)(b * EE + e) * SS + m0) * HH, w2b + ((size_t)e * DD + n0) * HH,
            HH, LDS, acc);
  GEMM_EPI_VARS();
#pragma unroll
  for (int i = 0; i < 4; ++i)
#pragma unroll
    for (int j = 0; j < 4; ++j) {
      const float bias = b2[e * DD + n0 + wn + j * 16 + fr16];
      ushort4 pk;
      pk.x = f2bf(acc[i][j][0] + bias);
      pk.y = f2bf(acc[i][j][1] + bias);
      pk.z = f2bf(acc[i][j][2] + bias);
      pk.w = f2bf(acc[i][j][3] + bias);
      // T[d][s], stride 132
      *(ushort4*)(LDS + (wn + j * 16 + fr16) * 132 + wm + i * 16 + r4) = pk;
    }
  __syncthreads();
  const int t = threadIdx.x;
#pragma unroll
  for (int jj = 0; jj < 8; ++jj) {
    const int dl = (t >> 4) + jj * 16;
    const int ml = (t & 15) * 8;
    int4 v = *(const int4*)(LDS + dl * 132 + ml);
    *(int4*)(SOT + ((size_t)b * DD + n0 + dl) * ESN + e * SS + m0 + ml) = v;
  }
}

__global__ __launch_bounds__(256) void k_img_mfma(const unsigned short* __restrict__ E16,
    const unsigned short* __restrict__ SOT, const float* __restrict__ rinv,
    float* __restrict__ out) {
  GEMM_PRE(16384);
  const int3 bi = xcd_map();
  const int b = bi.z, m0 = bi.x * 128, n0 = bi.y * 128;
  gemm_core(E16 + ((size_t)b * NT + m0) * ESN, SOT + ((size_t)b * DD + n0) * ESN,
            ESN, LDS, acc);
  GEMM_EPI_VARS();
#pragma unroll
  for (int i = 0; i < 4; ++i)
#pragma unroll
    for (int j = 0; j < 4; ++j) {
      const int gmb = m0 + wm + i * 16 + r4;
      const int gn = n0 + wn + j * 16 + fr16;
#pragma unroll
      for (int r = 0; r < 4; ++r)
        out[((size_t)b * SEQ + 1 + gmb + r) * DD + gn] = acc[i][j][r] * rinv[b * NT + gmb + r];
    }
}

// -------- packing --------
__global__ __launch_bounds__(256) void k_xnf(const float* __restrict__ x, float* __restrict__ xnf) {
  const int wid = blockIdx.x * 4 + (threadIdx.x >> 6);
  const int lane = threadIdx.x & 63;
  const int b = wid >> 11;
  const float* row = x + ((size_t)b * SEQ + 1 + (wid & (NT - 1))) * DD;
  float s = 0.f;
#pragma unroll
  for (int k = 0; k < DD / 64; ++k) { const float v = row[lane + k * 64]; s = fmaf(v, v, s); }
  s = wave_sum(s);
  if (lane == 0) xnf[wid] = 1.0f / fmaxf(sqrtf(s), 1e-12f);
}

__global__ __launch_bounds__(256) void k_munf(const float* __restrict__ mu,
    const float* __restrict__ scale, float* __restrict__ munf) {
  __shared__ float part[4][64];
  const int c0 = blockIdx.x * 64;
  const int ci = threadIdx.x & 63, dg = threadIdx.x >> 6;
  float s = 0.f;
  for (int d = dg; d < DD; d += 4) { const float v = mu[(size_t)d * ESN + c0 + ci]; s = fmaf(v, v, s); }
  part[dg][ci] = s;
  __syncthreads();
  if (threadIdx.x < 64) {
    const float t = part[0][ci] + part[1][ci] + part[2][ci] + part[3][ci];
    munf[c0 + ci] = scale[0] / fmaxf(sqrtf(t), 1e-12f);
  }
}

__global__ __launch_bounds__(256) void k_pack_x(const float* __restrict__ x,
    const float* __restrict__ xnf, unsigned short* __restrict__ Xb,
    unsigned short* __restrict__ XT) {
  __shared__ unsigned short tile[64][72];
  const int b = blockIdx.z, n0 = blockIdx.x * 64, d0 = blockIdx.y * 64;
  const int t = threadIdx.x, tr = t >> 2, tc = (t & 3) * 16;
  const float* s = x + ((size_t)b * SEQ + 1 + n0 + tr) * DD + d0 + tc;
  const float xs = xnf[b * NT + n0 + tr];
  unsigned short tmp[16];
#pragma unroll
  for (int j = 0; j < 16; j += 4) {
    float4 v = *(const float4*)(s + j);
    tmp[j] = f2bf(v.x * xs); tmp[j + 1] = f2bf(v.y * xs);
    tmp[j + 2] = f2bf(v.z * xs); tmp[j + 3] = f2bf(v.w * xs);
  }
  *(int4*)&tile[tr][tc] = *(int4*)tmp;
  *(int4*)&tile[tr][tc + 8] = *(int4*)(tmp + 8);
  unsigned short* xb = Xb + ((size_t)b * NT + n0 + tr) * DD + d0 + tc;
  *(int4*)xb = *(int4*)tmp;
  *(int4*)(xb + 8) = *(int4*)(tmp + 8);
  __syncthreads();
  unsigned short* d = XT + ((size_t)b * DD + d0 + tr) * NT + n0 + tc;
#pragma unroll
  for (int j = 0; j < 16; ++j) tmp[j] = tile[tc + j][tr];
  *(int4*)d = *(int4*)tmp;
  *(int4*)(d + 8) = *(int4*)(tmp + 8);
}

__global__ __launch_bounds__(256) void k_pack_mu(const float* __restrict__ mu,
    const float* __restrict__ munf, unsigned short* __restrict__ MT) {
  __shared__ unsigned short tile[64][72];
  const int d0 = blockIdx.x * 64, c0 = blockIdx.y * 64;
  const int t = threadIdx.x, tr = t >> 2, tc = (t & 3) * 16;
  const float* s = mu + (size_t)(d0 + tr) * ESN + c0 + tc;
  unsigned short tmp[16];
#pragma unroll
  for (int j = 0; j < 16; j += 4) {
    float4 v = *(const float4*)(s + j);
    tmp[j] = f2bf(v.x * munf[c0 + tc + j]);
    tmp[j + 1] = f2bf(v.y * munf[c0 + tc + j + 1]);
    tmp[j + 2] = f2bf(v.z * munf[c0 + tc + j + 2]);
    tmp[j + 3] = f2bf(v.w * munf[c0 + tc + j + 3]);
  }
  *(int4*)&tile[tr][tc] = *(int4*)tmp;
  *(int4*)&tile[tr][tc + 8] = *(int4*)(tmp + 8);
  __syncthreads();
  unsigned short* d = MT + (size_t)(c0 + tr) * DD + d0 + tc;
#pragma unroll
  for (int j = 0; j < 16; ++j) tmp[j] = tile[tc + j][tr];
  *(int4*)d = *(int4*)tmp;
  *(int4*)(d + 8) = *(int4*)(tmp + 8);
}

__global__ __launch_bounds__(256) void k_packw(const float* __restrict__ w,
    unsigned short* __restrict__ o, int n4) {
  const int i = blockIdx.x * 256 + threadIdx.x;
  if (i < n4) {
    float4 v = ((const float4*)w)[i];
    ushort4 u;
    u.x = f2bf(v.x); u.y = f2bf(v.y); u.z = f2bf(v.z); u.w = f2bf(v.w);
    ((ushort4*)o)[i] = u;
  }
}

// -------- softmax stats --------
__global__ __launch_bounds__(256) void k_rowstats_e(const unsigned short* __restrict__ E,
    float* __restrict__ rinv, float* __restrict__ t_r2, float* __restrict__ t_dr) {
  const int wid = blockIdx.x * 4 + (threadIdx.x >> 6);  // b*NT + n
  const int lane = threadIdx.x & 63;
  const int n = wid & (NT - 1);
  const unsigned short* row = E + (size_t)wid * ESN;
  float s1 = 0.f, s2 = 0.f;
#pragma unroll
  for (int it = 0; it < 4; ++it) {
    int4 v = *(const int4*)(row + it * 512 + lane * 8);
    const unsigned short* u = (const unsigned short*)&v;
#pragma unroll
    for (int j = 0; j < 8; ++j) { const float e = bf2f(u[j]); s1 += e; s2 = fmaf(e, e, s2); }
  }
  s1 = wave_sum(s1); s2 = wave_sum(s2);
  if (lane == 0) {
    const float ri = 1.0f / s1;
    rinv[wid] = ri;
    const float r2 = 1.0f / (s2 * ri * ri + 1e-9f);
    t_r2[wid] = r2;
    t_dr[wid] = bf2f(row[n]) * ri * r2;
  }
}

__global__ __launch_bounds__(256) void k_colstats(const unsigned short* __restrict__ ET,
    float* __restrict__ cinv, float* __restrict__ t_rs2, float* __restrict__ t_sd) {
  const int wid = blockIdx.x * 4 + (threadIdx.x >> 6);  // b*ESN + c
  const int lane = threadIdx.x & 63;
  const unsigned short* row = ET + (size_t)wid * NT;
  float s1 = 0.f, s2 = 0.f;
#pragma unroll
  for (int it = 0; it < 4; ++it) {
    int4 v = *(const int4*)(row + it * 512 + lane * 8);
    const unsigned short* u = (const unsigned short*)&v;
#pragma unroll
    for (int j = 0; j < 8; ++j) { const float e = bf2f(u[j]); s1 += e; s2 = fmaf(e, e, s2); }
  }
  s1 = wave_sum(s1); s2 = wave_sum(s2);
  if (lane == 0) {
    const float ci = 1.0f / s1;
    cinv[wid] = ci;
    const float rs2 = 1.0f / (s2 * ci * ci + 1e-9f);
    t_rs2[wid] = rs2;
    const int c = wid & (ESN - 1);
    t_sd[wid] = ((c % 257) == 0) ? rs2 : 0.f;
  }
}

// -------- cls path --------
__global__ __launch_bounds__(256) void k_clsA(const float* __restrict__ x,
    const float* __restrict__ w1, const float* __restrict__ b1, float* __restrict__ clsh) {
  const int wid = blockIdx.x * 4 + (threadIdx.x >> 6);
  const int lane = threadIdx.x & 63;
  const int b = wid >> 9, h = wid & (HH - 1);
  const float* xr = x + (size_t)b * SEQ * DD;
  const float* wr = w1 + (size_t)h * DD;
  float s = 0.f;
#pragma unroll
  for (int k = 0; k < DD / 64; ++k) s = fmaf(xr[lane + k * 64], wr[lane + k * 64], s);
  s = wave_sum(s);
  if (lane == 0) clsh[wid] = gelu_f(s + b1[h]);
}

__global__ __launch_bounds__(256) void k_clsB(const float* __restrict__ clsh,
    const float* __restrict__ w2, const float* __restrict__ b2, float* __restrict__ out) {
  const int wid = blockIdx.x * 4 + (threadIdx.x >> 6);
  const int lane = threadIdx.x & 63;
  const int b = wid >> 10, d = wid & (DD - 1);
  const float* hr = clsh + (size_t)b * HH;
  const float* wr = w2 + (size_t)d * HH;
  float s = 0.f;
#pragma unroll
  for (int k = 0; k < HH / 64; ++k) s = fmaf(hr[lane + k * 64], wr[lane + k * 64], s);
  s = wave_sum(s);
  if (lane == 0) out[(size_t)b * SEQ * DD + d] = s + b2[d];
}

__global__ __launch_bounds__(256) void k_metrics(const float* __restrict__ t_r2,
    const float* __restrict__ t_dr, const float* __restrict__ t_rs2,
    const float* __restrict__ t_sd, float* __restrict__ out) {
  __shared__ float sm[256];
  const int tid = threadIdx.x;
  float a = 0.f, b = 0.f, c = 0.f, d = 0.f;
  for (int i = tid; i < BB * NT; i += 256) { a += t_r2[i]; b += t_dr[i]; }
  for (int i = tid; i < BB * ESN; i += 256) { c += t_rs2[i]; d += t_sd[i]; }
  float vals[4] = {a, b, c, d};
  float res[4];
#pragma unroll
  for (int v = 0; v < 4; ++v) {
    sm[tid] = vals[v];
    __syncthreads();
    for (int s = 128; s > 0; s >>= 1) {
      if (tid < s) sm[tid] += sm[tid + s];
      __syncthreads();
    }
    res[v] = sm[0];
    __syncthreads();
  }
  if (tid == 0) {
    out[(size_t)BB * SEQ * DD] = (res[0] - res[1]) / 33538048.0f;
    out[(size_t)BB * SEQ * DD + 1] = (res[2] - res[3]) / 33538048.0f;
  }
}

extern "C" void kernel_launch(void* const* d_in, const int* in_sizes, int n_in,
                              void* d_out, int out_size, void* d_ws, size_t ws_size,
                              hipStream_t stream) {
  const float* x      = (const float*)d_in[0];
  const float* mu     = (const float*)d_in[1];
  const float* scale  = (const float*)d_in[2];
  const float* cls_w1 = (const float*)d_in[3];
  const float* cls_b1 = (const float*)d_in[4];
  const float* cls_w2 = (const float*)d_in[5];
  const float* cls_b2 = (const float*)d_in[6];
  const float* w1     = (const float*)d_in[7];
  const float* b1     = (const float*)d_in[8];
  const float* w2     = (const float*)d_in[9];
  const float* b2     = (const float*)d_in[10];
  float* out = (float*)d_out;

  // workspace plan (bytes), aliasing by lifetime:
  char* W = (char*)d_ws;
  unsigned short* XT  = (unsigned short*)(W);              // 32MB; H1 aliases after slotin
  unsigned short* Xb  = (unsigned short*)(W + 33554432);   // 32MB; SOT aliases after logits
  unsigned short* MT  = (unsigned short*)(W + 67108864);   //  4MB
  unsigned short* E16 = (unsigned short*)(W + 71303168);   // 64MB (lives until img)
  unsigned short* ET  = (unsigned short*)(W + 138412032);  // 64MB; w1b/w2b alias after slotin
  unsigned short* SI  = (unsigned short*)(W + 205520896);  // 32MB
  unsigned short* H1  = (unsigned short*)(W);              // 16MB (alias XT)
  unsigned short* SOT = (unsigned short*)(W + 33554432);   // 32MB (alias Xb)
  unsigned short* w1b = (unsigned short*)(W + 138412032);  //  8MB (alias ET)
  unsigned short* w2b = (unsigned short*)(W + 146800640);  //  8MB (alias ET)
  float* F = (float*)(W + 239075328);
  float* xnf   = F;
  float* munf  = F + 16384;
  float* rinv  = F + 18432;
  float* t_r2  = F + 34816;
  float* t_dr  = F + 51200;
  float* cinv  = F + 67584;
  float* t_rs2 = F + 83968;
  float* t_sd  = F + 100352;
  float* clsh  = F + 116736;

  k_xnf<<<dim3(BB * NT / 4), 256, 0, stream>>>(x, xnf);
  k_munf<<<dim3(ESN / 64), 256, 0, stream>>>(mu, scale, munf);
  k_pack_x<<<dim3(NT / 64, DD / 64, BB), 256, 0, stream>>>(x, xnf, Xb, XT);
  k_pack_mu<<<dim3(DD / 64, ESN / 64), 256, 0, stream>>>(mu, munf, MT);
  k_logits_mfma<<<dim3(NT / 128, ESN / 128, BB), 256, 0, stream>>>(Xb, MT, E16, ET);
  k_rowstats_e<<<dim3(BB * NT / 4), 256, 0, stream>>>(E16, rinv, t_r2, t_dr);
  k_colstats<<<dim3(BB * ESN / 4), 256, 0, stream>>>(ET, cinv, t_rs2, t_sd);
  k_slotin_mfma<<<dim3(ESN / 128, DD / 128, BB), 256, 0, stream>>>(ET, XT, cinv, SI);
  k_packw<<<dim3(EE * HH * DD / 4 / 256), 256, 0, stream>>>(w1, w1b, EE * HH * DD / 4);
  k_packw<<<dim3(EE * DD * HH / 4 / 256), 256, 0, stream>>>(w2, w2b, EE * DD * HH / 4);
  k_ffn1_mfma<<<dim3(SS / 128, HH / 128, BB * EE), 256, 0, stream>>>(SI, w1b, b1, H1);
  k_ffn2_mfma<<<dim3(SS / 128, DD / 128, BB * EE), 256, 0, stream>>>(H1, w2b, b2, SOT);
  k_img_mfma<<<dim3(NT / 128, DD / 128, BB), 256, 0, stream>>>(E16, SOT, rinv, out);
  k_clsA<<<dim3(BB * HH / 4), 256, 0, stream>>>(x, cls_w1, cls_b1, clsh);
  k_clsB<<<dim3(BB * DD / 4), 256, 0, stream>>>(clsh, cls_w2, cls_b2, out);
  k_metrics<<<1, 256, 0, stream>>>(t_r2, t_dr, t_rs2, t_sd, out);
}

// Round 5
// 622.946 us; speedup vs baseline: 1.3731x; 1.3097x over previous
//
#include <hip/hip_runtime.h>
#include <math.h>

// Shapes (fixed)
#define BB 8
#define SEQ 2049
#define NT 2048
#define DD 1024
#define EE 8
#define SS 256
#define ESN 2048
#define HH 512

typedef __bf16 bf16x8 __attribute__((ext_vector_type(8)));
typedef float f32x4 __attribute__((ext_vector_type(4)));

__device__ __forceinline__ float gelu_f(float v) {
  return 0.5f * v * (1.0f + erff(v * 0.70710678118654752440f));
}
__device__ __forceinline__ float wave_sum(float v) {
#pragma unroll
  for (int off = 1; off < 64; off <<= 1) v += __shfl_xor(v, off);
  return v;
}
__device__ __forceinline__ unsigned short f2bf(float f) {
  unsigned int u = __float_as_uint(f);
  u = (u + 0x7fffu + ((u >> 16) & 1u)) >> 16;
  return (unsigned short)u;
}
__device__ __forceinline__ float bf2f(unsigned short h) {
  return __uint_as_float(((unsigned int)h) << 16);
}

// async 16B/lane global->LDS stage; lbase is wave-uniform, HW adds lane*16.
__device__ __forceinline__ void stage16(const unsigned short* g, unsigned short* lbase, int lane) {
#if __has_builtin(__builtin_amdgcn_global_load_lds)
  __builtin_amdgcn_global_load_lds((const __attribute__((address_space(1))) void*)g,
                                   (__attribute__((address_space(3))) void*)lbase, 16, 0, 0);
#else
  *(int4*)(lbase + lane * 8) = *(const int4*)g;
#endif
}

// ---- bf16 gemm_bt core (round-2 known-good): C[128x128]=A[m][k]*B[n][k]^T ----
// 256 threads = 4 waves (2x2 of 64x64). LDS tiles [128][32] bf16 linear.
// Single-buffered BK=32: stage -> barrier -> compute -> barrier.
__device__ __forceinline__ void gemm_core(const unsigned short* __restrict__ A,
                                          const unsigned short* __restrict__ B,
                                          int K, unsigned short* As, unsigned short* Bs,
                                          f32x4 acc[4][4]) {
  const int t = threadIdx.x;
  const int lane = t & 63, wave = t >> 6;
  const int srow = t >> 2, scol = (t & 3) * 8;
  const int fr = lane & 15, fk = (lane >> 4) * 8;
  const int wm = (wave >> 1) * 64, wn = (wave & 1) * 64;
  const unsigned short* a0 = A + (size_t)srow * K + scol;
  const unsigned short* a1 = A + (size_t)(srow + 64) * K + scol;
  const unsigned short* b0 = B + (size_t)srow * K + scol;
  const unsigned short* b1 = B + (size_t)(srow + 64) * K + scol;
  unsigned short* lA0 = As + wave * 512;
  unsigned short* lA1 = As + 2048 + wave * 512;
  unsigned short* lB0 = Bs + wave * 512;
  unsigned short* lB1 = Bs + 2048 + wave * 512;
  for (int k0 = 0; k0 < K; k0 += 32) {
    stage16(a0 + k0, lA0, lane);
    stage16(a1 + k0, lA1, lane);
    stage16(b0 + k0, lB0, lane);
    stage16(b1 + k0, lB1, lane);
    __syncthreads();  // drains vmcnt: staged tiles visible
    bf16x8 af[4], bfr[4];
#pragma unroll
    for (int i = 0; i < 4; ++i)
      af[i] = *(const bf16x8*)(As + (wm + i * 16 + fr) * 32 + fk);
#pragma unroll
    for (int j = 0; j < 4; ++j)
      bfr[j] = *(const bf16x8*)(Bs + (wn + j * 16 + fr) * 32 + fk);
#pragma unroll
    for (int i = 0; i < 4; ++i)
#pragma unroll
      for (int j = 0; j < 4; ++j)
        acc[i][j] = __builtin_amdgcn_mfma_f32_16x16x32_bf16(af[i], bfr[j], acc[i][j], 0, 0, 0);
    __syncthreads();  // all reads done before next stage overwrites
  }
}

#define ACC_INIT()                                        \
  f32x4 acc[4][4];                                        \
  _Pragma("unroll") for (int i = 0; i < 4; ++i)           \
  _Pragma("unroll") for (int j = 0; j < 4; ++j)           \
  _Pragma("unroll") for (int r = 0; r < 4; ++r) acc[i][j][r] = 0.f;

#define GEMM_EPI_VARS()                                   \
  const int lane = threadIdx.x & 63, wave = threadIdx.x >> 6; \
  const int wm = (wave >> 1) * 64, wn = (wave & 1) * 64;  \
  const int fr16 = lane & 15, r4 = (lane >> 4) << 2;

// logits -> E16[n][c] direct (32B runs) + ET[c][n] via chunked LDS transpose.
// LDS: union of gemm (8192 shorts) and 64x132 transpose chunk (8448 shorts).
__global__ __launch_bounds__(256) void k_logits_mfma(const unsigned short* __restrict__ Xb,
    const unsigned short* __restrict__ MT, unsigned short* __restrict__ E16,
    unsigned short* __restrict__ ET) {
  __shared__ unsigned short LDS[8448];
  ACC_INIT();
  const int b = blockIdx.z, m0 = blockIdx.x * 128, n0 = blockIdx.y * 128;
  gemm_core(Xb + ((size_t)b * NT + m0) * DD, MT + (size_t)n0 * DD, DD, LDS, LDS + 4096, acc);
  GEMM_EPI_VARS();
  const int t = threadIdx.x;
  unsigned short* o = E16 + (size_t)b * NT * ESN;
#pragma unroll
  for (int i = 0; i < 4; ++i)
#pragma unroll
    for (int j = 0; j < 4; ++j) {
      const int gmb = m0 + wm + i * 16 + r4;
      const int gn = n0 + wn + j * 16 + fr16;
      o[(size_t)(gmb + 0) * ESN + gn] = f2bf(expf(acc[i][j][0]));
      o[(size_t)(gmb + 1) * ESN + gn] = f2bf(expf(acc[i][j][1]));
      o[(size_t)(gmb + 2) * ESN + gn] = f2bf(expf(acc[i][j][2]));
      o[(size_t)(gmb + 3) * ESN + gn] = f2bf(expf(acc[i][j][3]));
    }
  // two 64-column chunks: chunk h handled by waves with wn == h*64
#pragma unroll
  for (int h = 0; h < 2; ++h) {
    if ((wn >> 6) == h) {
#pragma unroll
      for (int i = 0; i < 4; ++i)
#pragma unroll
        for (int j = 0; j < 4; ++j) {
          ushort4 pk;
          pk.x = f2bf(expf(acc[i][j][0]));
          pk.y = f2bf(expf(acc[i][j][1]));
          pk.z = f2bf(expf(acc[i][j][2]));
          pk.w = f2bf(expf(acc[i][j][3]));
          // T[n-local][m-local], stride 132 (8B-aligned rows)
          *(ushort4*)(LDS + (j * 16 + fr16) * 132 + wm + i * 16 + r4) = pk;
        }
    }
    __syncthreads();
#pragma unroll
    for (int p = 0; p < 4; ++p) {
      const int nl = p * 16 + (t >> 4);
      const int ml = (t & 15) * 8;
      int4 v = *(const int4*)(LDS + nl * 132 + ml);
      *(int4*)(ET + ((size_t)b * ESN + n0 + h * 64 + nl) * NT + m0 + ml) = v;
    }
    __syncthreads();
  }
}

__global__ __launch_bounds__(256) void k_slotin_mfma(const unsigned short* __restrict__ ET,
    const unsigned short* __restrict__ XT, const float* __restrict__ cinv,
    unsigned short* __restrict__ SI) {
  __shared__ unsigned short LDS[8192];
  ACC_INIT();
  const int b = blockIdx.z, m0 = blockIdx.x * 128, n0 = blockIdx.y * 128;
  gemm_core(ET + ((size_t)b * ESN + m0) * NT, XT + ((size_t)b * DD + n0) * NT, NT,
            LDS, LDS + 4096, acc);
  GEMM_EPI_VARS();
#pragma unroll
  for (int i = 0; i < 4; ++i)
#pragma unroll
    for (int j = 0; j < 4; ++j) {
      const int gmb = m0 + wm + i * 16 + r4;
      const int gn = n0 + wn + j * 16 + fr16;
#pragma unroll
      for (int r = 0; r < 4; ++r)
        SI[((size_t)b * ESN + gmb + r) * DD + gn] = f2bf(acc[i][j][r] * cinv[b * ESN + gmb + r]);
    }
}

__global__ __launch_bounds__(256) void k_ffn1_mfma(const unsigned short* __restrict__ SI,
    const unsigned short* __restrict__ w1b, const float* __restrict__ b1,
    unsigned short* __restrict__ H1) {
  __shared__ unsigned short LDS[8192];
  ACC_INIT();
  const int z = blockIdx.z, b = z >> 3, e = z & 7;
  const int m0 = blockIdx.x * 128, n0 = blockIdx.y * 128;
  gemm_core(SI + ((size_t)b * ESN + e * SS + m0) * DD, w1b + ((size_t)e * HH + n0) * DD,
            DD, LDS, LDS + 4096, acc);
  GEMM_EPI_VARS();
#pragma unroll
  for (int i = 0; i < 4; ++i)
#pragma unroll
    for (int j = 0; j < 4; ++j) {
      const int gmb = m0 + wm + i * 16 + r4;
      const int gn = n0 + wn + j * 16 + fr16;
      const float bias = b1[e * HH + gn];
#pragma unroll
      for (int r = 0; r < 4; ++r)
        H1[((size_t)(b * EE + e) * SS + gmb + r) * HH + gn] = f2bf(gelu_f(acc[i][j][r] + bias));
    }
}

// ffn2 -> SOT[d][c] via chunked LDS transpose (coalesced 256B rows)
__global__ __launch_bounds__(256) void k_ffn2_mfma(const unsigned short* __restrict__ H1,
    const unsigned short* __restrict__ w2b, const float* __restrict__ b2,
    unsigned short* __restrict__ SOT) {
  __shared__ unsigned short LDS[8448];
  ACC_INIT();
  const int z = blockIdx.z, b = z >> 3, e = z & 7;
  const int m0 = blockIdx.x * 128, n0 = blockIdx.y * 128;   // m: s within expert, n: d
  gemm_core(H1 + ((size_t)(b * EE + e) * SS + m0) * HH, w2b + ((size_t)e * DD + n0) * HH,
            HH, LDS, LDS + 4096, acc);
  GEMM_EPI_VARS();
  const int t = threadIdx.x;
#pragma unroll
  for (int h = 0; h < 2; ++h) {
    if ((wn >> 6) == h) {
#pragma unroll
      for (int i = 0; i < 4; ++i)
#pragma unroll
        for (int j = 0; j < 4; ++j) {
          const float bias = b2[e * DD + n0 + wn + j * 16 + fr16];
          ushort4 pk;
          pk.x = f2bf(acc[i][j][0] + bias);
          pk.y = f2bf(acc[i][j][1] + bias);
          pk.z = f2bf(acc[i][j][2] + bias);
          pk.w = f2bf(acc[i][j][3] + bias);
          *(ushort4*)(LDS + (j * 16 + fr16) * 132 + wm + i * 16 + r4) = pk;
        }
    }
    __syncthreads();
#pragma unroll
    for (int p = 0; p < 4; ++p) {
      const int dl = p * 16 + (t >> 4);
      const int ml = (t & 15) * 8;
      int4 v = *(const int4*)(LDS + dl * 132 + ml);
      *(int4*)(SOT + ((size_t)b * DD + n0 + h * 64 + dl) * ESN + e * SS + m0 + ml) = v;
    }
    __syncthreads();
  }
}

__global__ __launch_bounds__(256) void k_img_mfma(const unsigned short* __restrict__ E16,
    const unsigned short* __restrict__ SOT, const float* __restrict__ rinv,
    float* __restrict__ out) {
  __shared__ unsigned short LDS[8192];
  ACC_INIT();
  const int b = blockIdx.z, m0 = blockIdx.x * 128, n0 = blockIdx.y * 128;
  gemm_core(E16 + ((size_t)b * NT + m0) * ESN, SOT + ((size_t)b * DD + n0) * ESN,
            ESN, LDS, LDS + 4096, acc);
  GEMM_EPI_VARS();
#pragma unroll
  for (int i = 0; i < 4; ++i)
#pragma unroll
    for (int j = 0; j < 4; ++j) {
      const int gmb = m0 + wm + i * 16 + r4;
      const int gn = n0 + wn + j * 16 + fr16;
#pragma unroll
      for (int r = 0; r < 4; ++r)
        out[((size_t)b * SEQ + 1 + gmb + r) * DD + gn] = acc[i][j][r] * rinv[b * NT + gmb + r];
    }
}

// -------- packing --------
__global__ __launch_bounds__(256) void k_xnf(const float* __restrict__ x, float* __restrict__ xnf) {
  const int wid = blockIdx.x * 4 + (threadIdx.x >> 6);
  const int lane = threadIdx.x & 63;
  const int b = wid >> 11;
  const float* row = x + ((size_t)b * SEQ + 1 + (wid & (NT - 1))) * DD;
  float s = 0.f;
#pragma unroll
  for (int k = 0; k < DD / 64; ++k) { const float v = row[lane + k * 64]; s = fmaf(v, v, s); }
  s = wave_sum(s);
  if (lane == 0) xnf[wid] = 1.0f / fmaxf(sqrtf(s), 1e-12f);
}

__global__ __launch_bounds__(256) void k_munf(const float* __restrict__ mu,
    const float* __restrict__ scale, float* __restrict__ munf) {
  __shared__ float part[4][64];
  const int c0 = blockIdx.x * 64;
  const int ci = threadIdx.x & 63, dg = threadIdx.x >> 6;
  float s = 0.f;
  for (int d = dg; d < DD; d += 4) { const float v = mu[(size_t)d * ESN + c0 + ci]; s = fmaf(v, v, s); }
  part[dg][ci] = s;
  __syncthreads();
  if (threadIdx.x < 64) {
    const float t = part[0][ci] + part[1][ci] + part[2][ci] + part[3][ci];
    munf[c0 + ci] = scale[0] / fmaxf(sqrtf(t), 1e-12f);
  }
}

__global__ __launch_bounds__(256) void k_pack_x(const float* __restrict__ x,
    const float* __restrict__ xnf, unsigned short* __restrict__ Xb,
    unsigned short* __restrict__ XT) {
  __shared__ unsigned short tile[64][72];
  const int b = blockIdx.z, n0 = blockIdx.x * 64, d0 = blockIdx.y * 64;
  const int t = threadIdx.x, tr = t >> 2, tc = (t & 3) * 16;
  const float* s = x + ((size_t)b * SEQ + 1 + n0 + tr) * DD + d0 + tc;
  const float xs = xnf[b * NT + n0 + tr];
  unsigned short tmp[16];
#pragma unroll
  for (int j = 0; j < 16; j += 4) {
    float4 v = *(const float4*)(s + j);
    tmp[j] = f2bf(v.x * xs); tmp[j + 1] = f2bf(v.y * xs);
    tmp[j + 2] = f2bf(v.z * xs); tmp[j + 3] = f2bf(v.w * xs);
  }
  *(int4*)&tile[tr][tc] = *(int4*)tmp;
  *(int4*)&tile[tr][tc + 8] = *(int4*)(tmp + 8);
  unsigned short* xb = Xb + ((size_t)b * NT + n0 + tr) * DD + d0 + tc;
  *(int4*)xb = *(int4*)tmp;
  *(int4*)(xb + 8) = *(int4*)(tmp + 8);
  __syncthreads();
  unsigned short* d = XT + ((size_t)b * DD + d0 + tr) * NT + n0 + tc;
#pragma unroll
  for (int j = 0; j < 16; ++j) tmp[j] = tile[tc + j][tr];
  *(int4*)d = *(int4*)tmp;
  *(int4*)(d + 8) = *(int4*)(tmp + 8);
}

__global__ __launch_bounds__(256) void k_pack_mu(const float* __restrict__ mu,
    const float* __restrict__ munf, unsigned short* __restrict__ MT) {
  __shared__ unsigned short tile[64][72];
  const int d0 = blockIdx.x * 64, c0 = blockIdx.y * 64;
  const int t = threadIdx.x, tr = t >> 2, tc = (t & 3) * 16;
  const float* s = mu + (size_t)(d0 + tr) * ESN + c0 + tc;
  unsigned short tmp[16];
#pragma unroll
  for (int j = 0; j < 16; j += 4) {
    float4 v = *(const float4*)(s + j);
    tmp[j] = f2bf(v.x * munf[c0 + tc + j]);
    tmp[j + 1] = f2bf(v.y * munf[c0 + tc + j + 1]);
    tmp[j + 2] = f2bf(v.z * munf[c0 + tc + j + 2]);
    tmp[j + 3] = f2bf(v.w * munf[c0 + tc + j + 3]);
  }
  *(int4*)&tile[tr][tc] = *(int4*)tmp;
  *(int4*)&tile[tr][tc + 8] = *(int4*)(tmp + 8);
  __syncthreads();
  unsigned short* d = MT + (size_t)(c0 + tr) * DD + d0 + tc;
#pragma unroll
  for (int j = 0; j < 16; ++j) tmp[j] = tile[tc + j][tr];
  *(int4*)d = *(int4*)tmp;
  *(int4*)(d + 8) = *(int4*)(tmp + 8);
}

__global__ __launch_bounds__(256) void k_packw(const float* __restrict__ w,
    unsigned short* __restrict__ o, int n4) {
  const int i = blockIdx.x * 256 + threadIdx.x;
  if (i < n4) {
    float4 v = ((const float4*)w)[i];
    ushort4 u;
    u.x = f2bf(v.x); u.y = f2bf(v.y); u.z = f2bf(v.z); u.w = f2bf(v.w);
    ((ushort4*)o)[i] = u;
  }
}

// -------- softmax stats --------
__global__ __launch_bounds__(256) void k_rowstats_e(const unsigned short* __restrict__ E,
    float* __restrict__ rinv, float* __restrict__ t_r2, float* __restrict__ t_dr) {
  const int wid = blockIdx.x * 4 + (threadIdx.x >> 6);  // b*NT + n
  const int lane = threadIdx.x & 63;
  const int n = wid & (NT - 1);
  const unsigned short* row = E + (size_t)wid * ESN;
  float s1 = 0.f, s2 = 0.f;
#pragma unroll
  for (int it = 0; it < 4; ++it) {
    int4 v = *(const int4*)(row + it * 512 + lane * 8);
    const unsigned short* u = (const unsigned short*)&v;
#pragma unroll
    for (int j = 0; j < 8; ++j) { const float e = bf2f(u[j]); s1 += e; s2 = fmaf(e, e, s2); }
  }
  s1 = wave_sum(s1); s2 = wave_sum(s2);
  if (lane == 0) {
    const float ri = 1.0f / s1;
    rinv[wid] = ri;
    const float r2 = 1.0f / (s2 * ri * ri + 1e-9f);
    t_r2[wid] = r2;
    t_dr[wid] = bf2f(row[n]) * ri * r2;
  }
}

__global__ __launch_bounds__(256) void k_colstats(const unsigned short* __restrict__ ET,
    float* __restrict__ cinv, float* __restrict__ t_rs2, float* __restrict__ t_sd) {
  const int wid = blockIdx.x * 4 + (threadIdx.x >> 6);  // b*ESN + c
  const int lane = threadIdx.x & 63;
  const unsigned short* row = ET + (size_t)wid * NT;
  float s1 = 0.f, s2 = 0.f;
#pragma unroll
  for (int it = 0; it < 4; ++it) {
    int4 v = *(const int4*)(row + it * 512 + lane * 8);
    const unsigned short* u = (const unsigned short*)&v;
#pragma unroll
    for (int j = 0; j < 8; ++j) { const float e = bf2f(u[j]); s1 += e; s2 = fmaf(e, e, s2); }
  }
  s1 = wave_sum(s1); s2 = wave_sum(s2);
  if (lane == 0) {
    const float ci = 1.0f / s1;
    cinv[wid] = ci;
    const float rs2 = 1.0f / (s2 * ci * ci + 1e-9f);
    t_rs2[wid] = rs2;
    const int c = wid & (ESN - 1);
    t_sd[wid] = ((c % 257) == 0) ? rs2 : 0.f;
  }
}

// -------- cls path --------
__global__ __launch_bounds__(256) void k_clsA(const float* __restrict__ x,
    const float* __restrict__ w1, const float* __restrict__ b1, float* __restrict__ clsh) {
  const int wid = blockIdx.x * 4 + (threadIdx.x >> 6);
  const int lane = threadIdx.x & 63;
  const int b = wid >> 9, h = wid & (HH - 1);
  const float* xr = x + (size_t)b * SEQ * DD;
  const float* wr = w1 + (size_t)h * DD;
  float s = 0.f;
#pragma unroll
  for (int k = 0; k < DD / 64; ++k) s = fmaf(xr[lane + k * 64], wr[lane + k * 64], s);
  s = wave_sum(s);
  if (lane == 0) clsh[wid] = gelu_f(s + b1[h]);
}

__global__ __launch_bounds__(256) void k_clsB(const float* __restrict__ clsh,
    const float* __restrict__ w2, const float* __restrict__ b2, float* __restrict__ out) {
  const int wid = blockIdx.x * 4 + (threadIdx.x >> 6);
  const int lane = threadIdx.x & 63;
  const int b = wid >> 10, d = wid & (DD - 1);
  const float* hr = clsh + (size_t)b * HH;
  const float* wr = w2 + (size_t)d * HH;
  float s = 0.f;
#pragma unroll
  for (int k = 0; k < HH / 64; ++k) s = fmaf(hr[lane + k * 64], wr[lane + k * 64], s);
  s = wave_sum(s);
  if (lane == 0) out[(size_t)b * SEQ * DD + d] = s + b2[d];
}

__global__ __launch_bounds__(256) void k_metrics(const float* __restrict__ t_r2,
    const float* __restrict__ t_dr, const float* __restrict__ t_rs2,
    const float* __restrict__ t_sd, float* __restrict__ out) {
  __shared__ float sm[256];
  const int tid = threadIdx.x;
  float a = 0.f, b = 0.f, c = 0.f, d = 0.f;
  for (int i = tid; i < BB * NT; i += 256) { a += t_r2[i]; b += t_dr[i]; }
  for (int i = tid; i < BB * ESN; i += 256) { c += t_rs2[i]; d += t_sd[i]; }
  float vals[4] = {a, b, c, d};
  float res[4];
#pragma unroll
  for (int v = 0; v < 4; ++v) {
    sm[tid] = vals[v];
    __syncthreads();
    for (int s = 128; s > 0; s >>= 1) {
      if (tid < s) sm[tid] += sm[tid + s];
      __syncthreads();
    }
    res[v] = sm[0];
    __syncthreads();
  }
  if (tid == 0) {
    out[(size_t)BB * SEQ * DD] = (res[0] - res[1]) / 33538048.0f;
    out[(size_t)BB * SEQ * DD + 1] = (res[2] - res[3]) / 33538048.0f;
  }
}

extern "C" void kernel_launch(void* const* d_in, const int* in_sizes, int n_in,
                              void* d_out, int out_size, void* d_ws, size_t ws_size,
                              hipStream_t stream) {
  const float* x      = (const float*)d_in[0];
  const float* mu     = (const float*)d_in[1];
  const float* scale  = (const float*)d_in[2];
  const float* cls_w1 = (const float*)d_in[3];
  const float* cls_b1 = (const float*)d_in[4];
  const float* cls_w2 = (const float*)d_in[5];
  const float* cls_b2 = (const float*)d_in[6];
  const float* w1     = (const float*)d_in[7];
  const float* b1     = (const float*)d_in[8];
  const float* w2     = (const float*)d_in[9];
  const float* b2     = (const float*)d_in[10];
  float* out = (float*)d_out;

  // workspace plan (bytes), aliasing by lifetime:
  char* W = (char*)d_ws;
  unsigned short* XT  = (unsigned short*)(W);              // 32MB; H1 aliases after slotin
  unsigned short* Xb  = (unsigned short*)(W + 33554432);   // 32MB; SOT aliases after logits
  unsigned short* MT  = (unsigned short*)(W + 67108864);   //  4MB
  unsigned short* E16 = (unsigned short*)(W + 71303168);   // 64MB (lives until img)
  unsigned short* ET  = (unsigned short*)(W + 138412032);  // 64MB; w1b/w2b alias after slotin
  unsigned short* SI  = (unsigned short*)(W + 205520896);  // 32MB
  unsigned short* H1  = (unsigned short*)(W);              // 16MB (alias XT)
  unsigned short* SOT = (unsigned short*)(W + 33554432);   // 32MB (alias Xb)
  unsigned short* w1b = (unsigned short*)(W + 138412032);  //  8MB (alias ET)
  unsigned short* w2b = (unsigned short*)(W + 146800640);  //  8MB (alias ET)
  float* F = (float*)(W + 239075328);
  float* xnf   = F;
  float* munf  = F + 16384;
  float* rinv  = F + 18432;
  float* t_r2  = F + 34816;
  float* t_dr  = F + 51200;
  float* cinv  = F + 67584;
  float* t_rs2 = F + 83968;
  float* t_sd  = F + 100352;
  float* clsh  = F + 116736;

  k_xnf<<<dim3(BB * NT / 4), 256, 0, stream>>>(x, xnf);
  k_munf<<<dim3(ESN / 64), 256, 0, stream>>>(mu, scale, munf);
  k_pack_x<<<dim3(NT / 64, DD / 64, BB), 256, 0, stream>>>(x, xnf, Xb, XT);
  k_pack_mu<<<dim3(DD / 64, ESN / 64), 256, 0, stream>>>(mu, munf, MT);
  k_logits_mfma<<<dim3(NT / 128, ESN / 128, BB), 256, 0, stream>>>(Xb, MT, E16, ET);
  k_rowstats_e<<<dim3(BB * NT / 4), 256, 0, stream>>>(E16, rinv, t_r2, t_dr);
  k_colstats<<<dim3(BB * ESN / 4), 256, 0, stream>>>(ET, cinv, t_rs2, t_sd);
  k_slotin_mfma<<<dim3(ESN / 128, DD / 128, BB), 256, 0, stream>>>(ET, XT, cinv, SI);
  k_packw<<<dim3(EE * HH * DD / 4 / 256), 256, 0, stream>>>(w1, w1b, EE * HH * DD / 4);
  k_packw<<<dim3(EE * DD * HH / 4 / 256), 256, 0, stream>>>(w2, w2b, EE * DD * HH / 4);
  k_ffn1_mfma<<<dim3(SS / 128, HH / 128, BB * EE), 256, 0, stream>>>(SI, w1b, b1, H1);
  k_ffn2_mfma<<<dim3(SS / 128, DD / 128, BB * EE), 256, 0, stream>>>(H1, w2b, b2, SOT);
  k_img_mfma<<<dim3(NT / 128, DD / 128, BB), 256, 0, stream>>>(E16, SOT, rinv, out);
  k_clsA<<<dim3(BB * HH / 4), 256, 0, stream>>>(x, cls_w1, cls_b1, clsh);
  k_clsB<<<dim3(BB * DD / 4), 256, 0, stream>>>(clsh, cls_w2, cls_b2, out);
  k_metrics<<<1, 256, 0, stream>>>(t_r2, t_dr, t_rs2, t_sd, out);
}